// Round 8
// baseline (584.260 us; speedup 1.0000x reference)
//
#include <hip/hip_runtime.h>
#include <math.h>

#define NEG_SLOPE 0.2f
#define EPSF 1e-16f

constexpr int FIN = 128;
constexpr int H1  = 4;
constexpr int C   = 64;
constexpr int HC  = 256;   // H1 * C

__device__ inline float wredsum(float v) {
#pragma unroll
    for (int off = 32; off; off >>= 1) v += __shfl_down(v, off);
    return v;
}
__device__ inline float wredmax(float v) {
#pragma unroll
    for (int off = 32; off; off >>= 1) v = fmaxf(v, __shfl_down(v, off));
    return v;
}
__device__ inline float4 wredmax4(float4 v) {
#pragma unroll
    for (int off = 32; off; off >>= 1) {
        v.x = fmaxf(v.x, __shfl_down(v.x, off));
        v.y = fmaxf(v.y, __shfl_down(v.y, off));
        v.z = fmaxf(v.z, __shfl_down(v.z, off));
        v.w = fmaxf(v.w, __shfl_down(v.w, off));
    }
    return v;
}
__device__ inline float4 wredsum4(float4 v) {
#pragma unroll
    for (int off = 32; off; off >>= 1) {
        v.x += __shfl_down(v.x, off);
        v.y += __shfl_down(v.y, off);
        v.z += __shfl_down(v.z, off);
        v.w += __shfl_down(v.w, off);
    }
    return v;
}
__device__ inline float4 bcast4(float4 v) {
    v.x = __shfl(v.x, 0); v.y = __shfl(v.y, 0);
    v.z = __shfl(v.z, 0); v.w = __shfl(v.w, 0);
    return v;
}
__device__ inline float comp4(float4 v, int i) {
    return i == 0 ? v.x : (i == 1 ? v.y : (i == 2 ? v.z : v.w));
}
__device__ inline unsigned short f2bf(float f) {   // RNE
    unsigned u = __float_as_uint(f);
    return (unsigned short)((u + 0x7fffu + ((u >> 16) & 1u)) >> 16);
}

// ---------- tiny prep ----------
__global__ void k_ea_sum(const float* __restrict__ ea, int E, float* __restrict__ scal) {
    int i = blockIdx.x * blockDim.x + threadIdx.x;
    float v = (i < E) ? ea[i] : 0.0f;
    v = wredsum(v);
    __shared__ float sm[4];
    if ((threadIdx.x & 63) == 0) sm[threadIdx.x >> 6] = v;
    __syncthreads();
    if (threadIdx.x == 0) atomicAdd(scal, sm[0] + sm[1] + sm[2] + sm[3]);
}

// scal[1]=ea_mean, scal[2]=we2dot, scal[4..7]=we1dot[h]
__global__ void k_prep(const float* __restrict__ We1, const float* __restrict__ ae1,
                       const float* __restrict__ We2, const float* __restrict__ ae2,
                       float* __restrict__ scal, float inv_E) {
    int t = threadIdx.x;
    float p = We1[t] * ae1[t];
    p = wredsum(p);
    if ((t & 63) == 0) scal[4 + (t >> 6)] = p;
    if (t < 64) {
        float q = We2[t] * ae2[t];
        q = wredsum(q);
        if (t == 0) scal[2] = q;
    }
    if (t == 0) scal[1] = scal[0] * inv_E;
}

// reorder weights: W1r[k/4][n][4], W2r[k/4][c][4]  (one float4 = 4 consecutive k-taps)
__global__ void k_reord(const float* __restrict__ W1, const float* __restrict__ W2,
                        float* __restrict__ W1r, float* __restrict__ W2r) {
    int idx = blockIdx.x * 256 + threadIdx.x;
    if (idx < FIN * HC) {
        int k = idx / HC, n = idx % HC;
        W1r[(((k >> 2) * HC) + n) * 4 + (k & 3)] = W1[idx];
    }
    if (idx < HC * C) {
        int k = idx / C, c = idx % C;
        W2r[(((k >> 2) * C) + c) * 4 + (k & 3)] = W2[idx];
    }
}

// ---------- CSR build (edges grouped by dst) ----------
__global__ void k_hist(const int* __restrict__ ei, int* __restrict__ deg, int E, int Etot) {
    int e = blockIdx.x * blockDim.x + threadIdx.x;
    if (e >= Etot) return;
    int d = (e < E) ? ei[E + e] : e - E;
    atomicAdd(&deg[d], 1);
}

__global__ void k_scan1(const int* __restrict__ deg, int* __restrict__ rowstart,
                        int* __restrict__ bsums, int N) {
    __shared__ int sm[256];
    int i = blockIdx.x * 256 + threadIdx.x;
    int v = (i < N) ? deg[i] : 0;
    sm[threadIdx.x] = v;
    __syncthreads();
    for (int off = 1; off < 256; off <<= 1) {
        int t = (threadIdx.x >= off) ? sm[threadIdx.x - off] : 0;
        __syncthreads();
        sm[threadIdx.x] += t;
        __syncthreads();
    }
    if (i < N) rowstart[i] = sm[threadIdx.x] - v;   // exclusive
    if (threadIdx.x == 255) bsums[blockIdx.x] = sm[255];
}

__global__ void k_scan2(int* __restrict__ bsums, int nb) {
    __shared__ int sm[256];
    int v = (threadIdx.x < nb) ? bsums[threadIdx.x] : 0;
    sm[threadIdx.x] = v;
    __syncthreads();
    for (int off = 1; off < 256; off <<= 1) {
        int t = (threadIdx.x >= off) ? sm[threadIdx.x - off] : 0;
        __syncthreads();
        sm[threadIdx.x] += t;
        __syncthreads();
    }
    if (threadIdx.x < nb) bsums[threadIdx.x] = sm[threadIdx.x] - v;   // exclusive
}

__global__ void k_scan3(int* __restrict__ rowstart, const int* __restrict__ bsums, int N) {
    int i = blockIdx.x * 256 + threadIdx.x;
    if (i < N) rowstart[i] += bsums[blockIdx.x];
}

__global__ void k_scatter(const int* __restrict__ ei, const float* __restrict__ eattr,
                          const float* __restrict__ scal, const int* __restrict__ rowstart,
                          int* __restrict__ cursor, int2* __restrict__ csr, int E, int Etot) {
    int e = blockIdx.x * blockDim.x + threadIdx.x;
    if (e >= Etot) return;
    int s, d; float ea;
    if (e < E) { s = ei[e]; d = ei[E + e]; ea = eattr[e]; }
    else       { s = e - E; d = s;          ea = scal[1]; }
    int pos = atomicAdd(&cursor[d], 1);
    csr[rowstart[d] + pos] = make_int2(s, __float_as_int(ea));
}

// ---------- layer 1 GEMM: h1(bf16) = x @ W1, scalar-broadcast x, no LDS ----------
// 16 nodes per block; thread t = output channel
__global__ void k_gemm1(const float* __restrict__ x, const float4* __restrict__ W1r,
                        const float* __restrict__ attsrc, const float* __restrict__ attdst,
                        unsigned short* __restrict__ h1b,
                        float* __restrict__ a_src, float* __restrict__ a_dst) {
    int n0 = blockIdx.x * 16;
    int t = threadIdx.x;
    const float4* xg = (const float4*)(x + (size_t)n0 * FIN);   // 16 rows x 32 float4
    float acc[16];
#pragma unroll
    for (int i = 0; i < 16; ++i) acc[i] = 0.0f;
#pragma unroll 2
    for (int k4 = 0; k4 < FIN / 4; ++k4) {
        float4 wv = W1r[k4 * HC + t];
#pragma unroll
        for (int i = 0; i < 16; ++i) {
            float4 xv = xg[i * 32 + k4];    // wave-uniform -> s_load + SGPR-operand FMA
            acc[i] = fmaf(xv.x, wv.x, fmaf(xv.y, wv.y,
                     fmaf(xv.z, wv.z, fmaf(xv.w, wv.w, acc[i]))));
        }
    }
    int g = t >> 6;   // head (wave id)
    float asr = attsrc[t], adr = attdst[t];
#pragma unroll
    for (int i = 0; i < 16; ++i) {
        h1b[(size_t)(n0 + i) * HC + t] = f2bf(acc[i]);
        float ps = wredsum(acc[i] * asr);
        float pd = wredsum(acc[i] * adr);
        if ((t & 63) == 0) {
            a_src[(n0 + i) * H1 + g] = ps;
            a_dst[(n0 + i) * H1 + g] = pd;
        }
    }
}

// ---------- layer 1 aggregation: ONE WAVE PER NODE, bf16 row gather (uint2/lane) ----------
// 4 nodes per 256-thread block; lane l covers channels 4l..4l+3 (head = l>>4)
__global__ void k_agg1(const int* __restrict__ rowstart, const int* __restrict__ deg,
                       const int2* __restrict__ csr,
                       const float* __restrict__ a_src, const float* __restrict__ a_dst,
                       const float* __restrict__ scal, const unsigned short* __restrict__ h1b,
                       const float* __restrict__ b1, float* __restrict__ out1) {
    __shared__ float4 wlds[4][64];   // [wave][edge-in-chunk] per-head weights, 4 KB
    int wid = threadIdx.x >> 6, lane = threadIdx.x & 63;
    int n = blockIdx.x * 4 + wid;
    int myh = lane >> 4;
    int rs = rowstart[n], cnt = deg[n];
    const float4 adv = ((const float4*)a_dst)[n];
    const float4 wh  = *((const float4*)(scal + 4));
    const uint2* h1v = (const uint2*)h1b;         // row stride = 64 uint2
    const float* wbase = (const float*)(&wlds[wid][0]) + myh;

    float4 M = make_float4(-INFINITY, -INFINITY, -INFINITY, -INFINITY);
    float4 den  = make_float4(0.f, 0.f, 0.f, 0.f);
    float4 acc0 = make_float4(0.f, 0.f, 0.f, 0.f);
    float4 acc1 = make_float4(0.f, 0.f, 0.f, 0.f);

    for (int base = 0; base < cnt; base += 64) {
        int j = base + lane;
        int sj = 0;
        float4 al = make_float4(-INFINITY, -INFINITY, -INFINITY, -INFINITY);
        if (j < cnt) {
            int2 cv = csr[rs + j];
            sj = cv.x;
            float ea = __int_as_float(cv.y);
            float4 as4 = ((const float4*)a_src)[sj];
            al.x = as4.x + adv.x + ea * wh.x;
            al.y = as4.y + adv.y + ea * wh.y;
            al.z = as4.z + adv.z + ea * wh.z;
            al.w = as4.w + adv.w + ea * wh.w;
            al.x = al.x > 0.f ? al.x : NEG_SLOPE * al.x;
            al.y = al.y > 0.f ? al.y : NEG_SLOPE * al.y;
            al.z = al.z > 0.f ? al.z : NEG_SLOPE * al.z;
            al.w = al.w > 0.f ? al.w : NEG_SLOPE * al.w;
        }
        float4 cm = bcast4(wredmax4(al));
        float4 newM = make_float4(fmaxf(M.x, cm.x), fmaxf(M.y, cm.y),
                                  fmaxf(M.z, cm.z), fmaxf(M.w, cm.w));
        float4 sc = make_float4(__expf(M.x - newM.x), __expf(M.y - newM.y),
                                __expf(M.z - newM.z), __expf(M.w - newM.w));
        den.x *= sc.x; den.y *= sc.y; den.z *= sc.z; den.w *= sc.w;
        float scm = comp4(sc, myh);
        acc0.x *= scm; acc0.y *= scm; acc0.z *= scm; acc0.w *= scm;
        acc1.x *= scm; acc1.y *= scm; acc1.z *= scm; acc1.w *= scm;
        M = newM;
        float4 w4 = make_float4(__expf(al.x - M.x), __expf(al.y - M.y),
                                __expf(al.z - M.z), __expf(al.w - M.w));
        den.x += w4.x; den.y += w4.y; den.z += w4.z; den.w += w4.w;
        wlds[wid][lane] = w4;
        int m = min(64, cnt - base);
        int jj = 0;
#pragma unroll 2
        for (; jj + 1 < m; jj += 2) {
            int s0 = __shfl(sj, jj);
            int s1 = __shfl(sj, jj + 1);
            float w0 = wbase[jj * 4];
            float w1 = wbase[jj * 4 + 4];
            uint2 v0 = h1v[(size_t)s0 * 64 + lane];
            uint2 v1 = h1v[(size_t)s1 * 64 + lane];
            acc0.x += __uint_as_float(v0.x << 16)          * w0;
            acc0.y += __uint_as_float(v0.x & 0xffff0000u)  * w0;
            acc0.z += __uint_as_float(v0.y << 16)          * w0;
            acc0.w += __uint_as_float(v0.y & 0xffff0000u)  * w0;
            acc1.x += __uint_as_float(v1.x << 16)          * w1;
            acc1.y += __uint_as_float(v1.x & 0xffff0000u)  * w1;
            acc1.z += __uint_as_float(v1.y << 16)          * w1;
            acc1.w += __uint_as_float(v1.y & 0xffff0000u)  * w1;
        }
        if (jj < m) {
            int s0 = __shfl(sj, jj);
            float w0 = wbase[jj * 4];
            uint2 v0 = h1v[(size_t)s0 * 64 + lane];
            acc0.x += __uint_as_float(v0.x << 16)          * w0;
            acc0.y += __uint_as_float(v0.x & 0xffff0000u)  * w0;
            acc0.z += __uint_as_float(v0.y << 16)          * w0;
            acc0.w += __uint_as_float(v0.y & 0xffff0000u)  * w0;
        }
    }
    float4 dsum = bcast4(wredsum4(den));
    float dt = comp4(dsum, myh) + EPSF;
    float inv = 1.0f / dt;
    float4 b4 = ((const float4*)b1)[lane];
    float4 v;
    v.x = (acc0.x + acc1.x) * inv + b4.x;
    v.y = (acc0.y + acc1.y) * inv + b4.y;
    v.z = (acc0.z + acc1.z) * inv + b4.z;
    v.w = (acc0.w + acc1.w) * inv + b4.w;
    v.x = v.x > 0.f ? v.x : expm1f(v.x);
    v.y = v.y > 0.f ? v.y : expm1f(v.y);
    v.z = v.z > 0.f ? v.z : expm1f(v.z);
    v.w = v.w > 0.f ? v.w : expm1f(v.w);
    ((float4*)(out1 + (size_t)n * HC))[lane] = v;
}

// ---------- layer 2 GEMM: h2(bf16) = out1 @ W2, scalar-broadcast rows, no LDS ----------
// 16 nodes per block; wave g handles nodes g, g+4, g+8, g+12; lane = output channel
__global__ void k_gemm2(const float* __restrict__ out1, const float4* __restrict__ W2r,
                        const float* __restrict__ attsrc, const float* __restrict__ attdst,
                        unsigned short* __restrict__ h2b,
                        float* __restrict__ a_src2, float* __restrict__ a_dst2) {
    int n0 = blockIdx.x * 16;
    int t = threadIdx.x;
    int c = t & 63, g = t >> 6;
    const float4* og = (const float4*)(out1 + (size_t)n0 * HC);   // 16 rows x 64 float4
    float acc[4] = {0, 0, 0, 0};
#pragma unroll 2
    for (int k4 = 0; k4 < HC / 4; ++k4) {
        float4 wv = W2r[k4 * C + c];
#pragma unroll
        for (int q = 0; q < 4; ++q) {
            float4 rv = og[(g + 4 * q) * 64 + k4];   // wave-uniform
            acc[q] = fmaf(rv.x, wv.x, fmaf(rv.y, wv.y,
                     fmaf(rv.z, wv.z, fmaf(rv.w, wv.w, acc[q]))));
        }
    }
    float asr = attsrc[c], adr = attdst[c];
#pragma unroll
    for (int q = 0; q < 4; ++q) {
        int n = n0 + g + 4 * q;
        h2b[(size_t)n * C + c] = f2bf(acc[q]);
        float ps = wredsum(acc[q] * asr);
        float pd = wredsum(acc[q] * adr);
        if (c == 0) { a_src2[n] = ps; a_dst2[n] = pd; }
    }
}

// ---------- layer 2 aggregation + classifier head: ONE WAVE PER NODE, bf16 gather ----------
// lane = eg*16 + li : edge-subgroup eg (4 edges in flight), channel-quad li
__global__ void k_agg2(const int* __restrict__ rowstart, const int* __restrict__ deg,
                       const int2* __restrict__ csr,
                       const float* __restrict__ a_src2, const float* __restrict__ a_dst2,
                       const float* __restrict__ scal, const unsigned short* __restrict__ h2b,
                       const float* __restrict__ b2, const float* __restrict__ Wfc,
                       const float* __restrict__ bfc, float* __restrict__ d_out, int N) {
    __shared__ float wlds[4][64];
    int wid = threadIdx.x >> 6, lane = threadIdx.x & 63;
    int n = blockIdx.x * 4 + wid;
    int eg = lane >> 4, li = lane & 15;
    int rs = rowstart[n], cnt = deg[n];
    float adv = a_dst2[n];
    float w2  = scal[2];
    const uint2* h2v = (const uint2*)h2b;   // row stride = 16 uint2 (64 bf16)

    float M = -INFINITY, den = 0.0f;
    float4 acc = make_float4(0.f, 0.f, 0.f, 0.f);

    for (int base = 0; base < cnt; base += 64) {
        int j = base + lane;
        int sj = 0; float al = -INFINITY;
        if (j < cnt) {
            int2 cv = csr[rs + j];
            sj = cv.x;
            al = a_src2[sj] + adv + __int_as_float(cv.y) * w2;
            al = al > 0.0f ? al : NEG_SLOPE * al;
        }
        float cm = wredmax(al); cm = __shfl(cm, 0);
        float newM = fmaxf(M, cm);
        float sc = __expf(M - newM);
        den *= sc;
        acc.x *= sc; acc.y *= sc; acc.z *= sc; acc.w *= sc;
        M = newM;
        float w = __expf(al - M);
        den += w;
        wlds[wid][lane] = w;
        int m = min(64, cnt - base);
#pragma unroll 4
        for (int jj = 0; jj < m; jj += 4) {
            int idx = jj + eg;                     // <= 63 always
            float ww = wlds[wid][idx];             // 0 for padded edges
            int   s  = __shfl(sj, idx);
            uint2 hv = h2v[(size_t)s * 16 + li];
            acc.x += __uint_as_float(hv.x << 16)         * ww;
            acc.y += __uint_as_float(hv.x & 0xffff0000u) * ww;
            acc.z += __uint_as_float(hv.y << 16)         * ww;
            acc.w += __uint_as_float(hv.y & 0xffff0000u) * ww;
        }
    }
    // reduce acc across the 4 edge-subgroups (lanes l, l+16, l+32, l+48)
#pragma unroll
    for (int off = 32; off >= 16; off >>= 1) {
        acc.x += __shfl_down(acc.x, off);
        acc.y += __shfl_down(acc.y, off);
        acc.z += __shfl_down(acc.z, off);
        acc.w += __shfl_down(acc.w, off);
    }
    float dt = wredsum(den); dt = __shfl(dt, 0);
    float inv = 1.0f / (dt + EPSF);
    float4 b4 = ((const float4*)b2)[li];
    float4 v;
    v.x = acc.x * inv + b4.x;
    v.y = acc.y * inv + b4.y;
    v.z = acc.z * inv + b4.z;
    v.w = acc.w * inv + b4.w;
    v.x = v.x > 0.f ? v.x : expm1f(v.x);
    v.y = v.y > 0.f ? v.y : expm1f(v.y);
    v.z = v.z > 0.f ? v.z : expm1f(v.z);
    v.w = v.w > 0.f ? v.w : expm1f(v.w);
    if (lane < 16)
        ((float4*)(d_out + (size_t)2 * N + (size_t)n * C))[li] = v;   // emb
    // classifier: channels 4li..4li+3 on lanes 0..15
    const float4* wfc4 = (const float4*)Wfc;
    float4 A = wfc4[li * 2], B = wfc4[li * 2 + 1];
    float p0 = v.x * A.x + v.y * A.z + v.z * B.x + v.w * B.z;
    float p1 = v.x * A.y + v.y * A.w + v.z * B.y + v.w * B.w;
#pragma unroll
    for (int off = 8; off; off >>= 1) {
        p0 += __shfl_down(p0, off);
        p1 += __shfl_down(p1, off);
    }
    if (lane == 0) {
        p0 += bfc[0]; p1 += bfc[1];
        float mm = fmaxf(p0, p1);
        float lse = mm + logf(__expf(p0 - mm) + __expf(p1 - mm));
        d_out[(size_t)n * 2]     = p0 - lse;
        d_out[(size_t)n * 2 + 1] = p1 - lse;
    }
}

extern "C" void kernel_launch(void* const* d_in, const int* in_sizes, int n_in,
                              void* d_out, int out_size, void* d_ws, size_t ws_size,
                              hipStream_t stream) {
    const float* x     = (const float*)d_in[0];
    const int*   ei    = (const int*)  d_in[1];
    const float* eattr = (const float*)d_in[2];
    const float* W1    = (const float*)d_in[3];
    const float* as1   = (const float*)d_in[4];
    const float* ad1   = (const float*)d_in[5];
    const float* We1   = (const float*)d_in[6];
    const float* ae1   = (const float*)d_in[7];
    const float* b1    = (const float*)d_in[8];
    const float* W2    = (const float*)d_in[9];
    const float* as2   = (const float*)d_in[10];
    const float* ad2   = (const float*)d_in[11];
    const float* We2   = (const float*)d_in[12];
    const float* ae2   = (const float*)d_in[13];
    const float* b2    = (const float*)d_in[14];
    const float* Wfc   = (const float*)d_in[15];
    const float* bfc   = (const float*)d_in[16];

    const int N    = in_sizes[0] / FIN;   // 50000
    const int E    = in_sizes[2];         // 800000
    const int Etot = E + N;

    char* wsb = (char*)d_ws;
    size_t off = 0;
    auto alloc = [&](size_t elems) {
        off = (off + 15) & ~(size_t)15;   // 16B align every buffer
        void* p = wsb + off; off += elems * 4; return p;
    };

    // ---- zero-initialized region (front) ----
    int*   deg    = (int*)  alloc(N);
    int*   cursor = (int*)  alloc(N);
    float* scal   = (float*)alloc(8);
    size_t zero_bytes = (off + 15) & ~(size_t)15;
    // ---- rest ----
    int*   rowstart = (int*)  alloc(N);
    int*   bsums    = (int*)  alloc(256);
    int2*  csr      = (int2*) alloc((size_t)Etot * 2);
    unsigned short* h1b = (unsigned short*)alloc((size_t)N * HC / 2);   // bf16
    unsigned short* h2b = (unsigned short*)alloc((size_t)N * C / 2);    // bf16
    float* out1     = (float*)alloc((size_t)N * HC);
    float* W1r      = (float*)alloc((size_t)FIN * HC);
    float* W2r      = (float*)alloc((size_t)HC * C);
    float* a_src1   = (float*)alloc((size_t)N * H1);
    float* a_dst1   = (float*)alloc((size_t)N * H1);
    float* a_src2   = (float*)alloc(N);
    float* a_dst2   = (float*)alloc(N);

    hipMemsetAsync(d_ws, 0, zero_bytes, stream);

    k_ea_sum<<<(E + 255) / 256, 256, 0, stream>>>(eattr, E, scal);
    k_prep<<<1, 256, 0, stream>>>(We1, ae1, We2, ae2, scal, 1.0f / (float)E);
    k_reord<<<(FIN * HC + 255) / 256, 256, 0, stream>>>(W1, W2, W1r, W2r);

    int ge = (Etot + 255) / 256;
    int nb = (N + 255) / 256;
    k_hist<<<ge, 256, 0, stream>>>(ei, deg, E, Etot);
    k_scan1<<<nb, 256, 0, stream>>>(deg, rowstart, bsums, N);
    k_scan2<<<1, 256, 0, stream>>>(bsums, nb);
    k_scan3<<<nb, 256, 0, stream>>>(rowstart, bsums, N);
    k_scatter<<<ge, 256, 0, stream>>>(ei, eattr, scal, rowstart, cursor, csr, E, Etot);

    k_gemm1<<<N / 16, 256, 0, stream>>>(x, (const float4*)W1r, as1, ad1, h1b, a_src1, a_dst1);
    k_agg1<<<N / 4, 256, 0, stream>>>(rowstart, deg, csr, a_src1, a_dst1, scal, h1b, b1, out1);
    k_gemm2<<<N / 16, 256, 0, stream>>>(out1, (const float4*)W2r, as2, ad2, h2b, a_src2, a_dst2);
    k_agg2<<<N / 4, 256, 0, stream>>>(rowstart, deg, csr, a_src2, a_dst2, scal, h2b,
                                      b2, Wfc, bfc, (float*)d_out, N);
}

// Round 9
// 383.741 us; speedup vs baseline: 1.5225x; 1.5225x over previous
//
#include <hip/hip_runtime.h>
#include <math.h>

#define NEG_SLOPE 0.2f
#define EPSF 1e-16f

constexpr int FIN = 128;
constexpr int H1  = 4;
constexpr int C   = 64;
constexpr int HC  = 256;   // H1 * C

typedef __attribute__((ext_vector_type(8))) short bf16x8;
typedef __attribute__((ext_vector_type(4))) float f32x4;

__device__ inline float wredsum(float v) {
#pragma unroll
    for (int off = 32; off; off >>= 1) v += __shfl_down(v, off);
    return v;
}
__device__ inline float wredmax(float v) {
#pragma unroll
    for (int off = 32; off; off >>= 1) v = fmaxf(v, __shfl_down(v, off));
    return v;
}
__device__ inline float4 wredmax4(float4 v) {
#pragma unroll
    for (int off = 32; off; off >>= 1) {
        v.x = fmaxf(v.x, __shfl_down(v.x, off));
        v.y = fmaxf(v.y, __shfl_down(v.y, off));
        v.z = fmaxf(v.z, __shfl_down(v.z, off));
        v.w = fmaxf(v.w, __shfl_down(v.w, off));
    }
    return v;
}
__device__ inline float4 wredsum4(float4 v) {
#pragma unroll
    for (int off = 32; off; off >>= 1) {
        v.x += __shfl_down(v.x, off);
        v.y += __shfl_down(v.y, off);
        v.z += __shfl_down(v.z, off);
        v.w += __shfl_down(v.w, off);
    }
    return v;
}
__device__ inline float4 bcast4(float4 v) {
    v.x = __shfl(v.x, 0); v.y = __shfl(v.y, 0);
    v.z = __shfl(v.z, 0); v.w = __shfl(v.w, 0);
    return v;
}
__device__ inline float comp4(float4 v, int i) {
    return i == 0 ? v.x : (i == 1 ? v.y : (i == 2 ? v.z : v.w));
}
__device__ inline unsigned short f2bf(float f) {   // RNE
    unsigned u = __float_as_uint(f);
    return (unsigned short)((u + 0x7fffu + ((u >> 16) & 1u)) >> 16);
}

// ---------- tiny prep ----------
__global__ void k_ea_sum(const float* __restrict__ ea, int E, float* __restrict__ scal) {
    int i = blockIdx.x * blockDim.x + threadIdx.x;
    float v = (i < E) ? ea[i] : 0.0f;
    v = wredsum(v);
    __shared__ float sm[4];
    if ((threadIdx.x & 63) == 0) sm[threadIdx.x >> 6] = v;
    __syncthreads();
    if (threadIdx.x == 0) atomicAdd(scal, sm[0] + sm[1] + sm[2] + sm[3]);
}

// scal[1]=ea_mean, scal[2]=we2dot, scal[4..7]=we1dot[h]
__global__ void k_prep(const float* __restrict__ We1, const float* __restrict__ ae1,
                       const float* __restrict__ We2, const float* __restrict__ ae2,
                       float* __restrict__ scal, float inv_E) {
    int t = threadIdx.x;
    float p = We1[t] * ae1[t];
    p = wredsum(p);
    if ((t & 63) == 0) scal[4 + (t >> 6)] = p;
    if (t < 64) {
        float q = We2[t] * ae2[t];
        q = wredsum(q);
        if (t == 0) scal[2] = q;
    }
    if (t == 0) scal[1] = scal[0] * inv_E;
}

// ---------- convert W1/W2 to bf16 MFMA fragment order ----------
// W1f flat: (((g*4+ct)*4 + t)*64 + l)*8 + j  <-  W1[(t*32+(l>>4)*8+j)*HC + 16*(g*4+ct) + (l&15)]
// W2f flat: ((g*8+t)*64 + l)*8 + j           <-  W2[(t*32+(l>>4)*8+j)*C  + 16*g + (l&15)]
__global__ void k_convw(const float* __restrict__ W1, const float* __restrict__ W2,
                        unsigned short* __restrict__ W1f, unsigned short* __restrict__ W2f) {
    int idx = blockIdx.x * 256 + threadIdx.x;   // 32768 total
    {
        int j = idx & 7, l = (idx >> 3) & 63, t = (idx >> 9) & 3, q = idx >> 11;
        int k = t * 32 + (l >> 4) * 8 + j;
        int n = 16 * q + (l & 15);
        W1f[idx] = f2bf(W1[k * HC + n]);
    }
    if (idx < 16384) {
        int j = idx & 7, l = (idx >> 3) & 63, t = (idx >> 9) & 7, g = idx >> 12;
        int k = t * 32 + (l >> 4) * 8 + j;
        int c = 16 * g + (l & 15);
        W2f[idx] = f2bf(W2[k * C + c]);
    }
}

// ---------- CSR build (edges grouped by dst) ----------
__global__ void k_hist(const int* __restrict__ ei, int* __restrict__ deg, int E, int Etot) {
    int e = blockIdx.x * blockDim.x + threadIdx.x;
    if (e >= Etot) return;
    int d = (e < E) ? ei[E + e] : e - E;
    atomicAdd(&deg[d], 1);
}

__global__ void k_scan1(const int* __restrict__ deg, int* __restrict__ rowstart,
                        int* __restrict__ bsums, int N) {
    __shared__ int sm[256];
    int i = blockIdx.x * 256 + threadIdx.x;
    int v = (i < N) ? deg[i] : 0;
    sm[threadIdx.x] = v;
    __syncthreads();
    for (int off = 1; off < 256; off <<= 1) {
        int t = (threadIdx.x >= off) ? sm[threadIdx.x - off] : 0;
        __syncthreads();
        sm[threadIdx.x] += t;
        __syncthreads();
    }
    if (i < N) rowstart[i] = sm[threadIdx.x] - v;   // exclusive
    if (threadIdx.x == 255) bsums[blockIdx.x] = sm[255];
}

__global__ void k_scan2(int* __restrict__ bsums, int nb) {
    __shared__ int sm[256];
    int v = (threadIdx.x < nb) ? bsums[threadIdx.x] : 0;
    sm[threadIdx.x] = v;
    __syncthreads();
    for (int off = 1; off < 256; off <<= 1) {
        int t = (threadIdx.x >= off) ? sm[threadIdx.x - off] : 0;
        __syncthreads();
        sm[threadIdx.x] += t;
        __syncthreads();
    }
    if (threadIdx.x < nb) bsums[threadIdx.x] = sm[threadIdx.x] - v;   // exclusive
}

__global__ void k_scan3(int* __restrict__ rowstart, const int* __restrict__ bsums, int N) {
    int i = blockIdx.x * 256 + threadIdx.x;
    if (i < N) rowstart[i] += bsums[blockIdx.x];
}

__global__ void k_scatter(const int* __restrict__ ei, const float* __restrict__ eattr,
                          const float* __restrict__ scal, const int* __restrict__ rowstart,
                          int* __restrict__ cursor, int2* __restrict__ csr, int E, int Etot) {
    int e = blockIdx.x * blockDim.x + threadIdx.x;
    if (e >= Etot) return;
    int s, d; float ea;
    if (e < E) { s = ei[e]; d = ei[E + e]; ea = eattr[e]; }
    else       { s = e - E; d = s;          ea = scal[1]; }
    int pos = atomicAdd(&cursor[d], 1);
    csr[rowstart[d] + pos] = make_int2(s, __float_as_int(ea));
}

// ---------- layer 1 GEMM via MFMA: h1(bf16) = x @ W1 ----------
// 16 rows/block, 4 waves; wave g = head g (cols 64g..64g+63): 4 col-tiles x 4 k-steps
__global__ void k_gemm1(const float* __restrict__ x, const unsigned short* __restrict__ W1f,
                        const float* __restrict__ attsrc, const float* __restrict__ attdst,
                        unsigned short* __restrict__ h1b,
                        float* __restrict__ a_src, float* __restrict__ a_dst) {
    __shared__ unsigned short xs[16 * 128];   // 4 KB, 16B-chunk swizzled
    __shared__ unsigned short hs[16 * 256];   // 8 KB repack
    int t = threadIdx.x;
    int n0 = blockIdx.x * 16;
    {   // stage-convert x -> bf16 LDS (thread t: row t>>4, chunk (t&15), swizzle ^(row&7))
        const float4* xg = (const float4*)(x + (size_t)n0 * FIN);
        float4 v0 = xg[t * 2], v1 = xg[t * 2 + 1];
        int row = t >> 4;
        int ch = (t & 15) ^ (row & 7);
        uint4 p;
        p.x = f2bf(v0.x) | ((unsigned)f2bf(v0.y) << 16);
        p.y = f2bf(v0.z) | ((unsigned)f2bf(v0.w) << 16);
        p.z = f2bf(v1.x) | ((unsigned)f2bf(v1.y) << 16);
        p.w = f2bf(v1.z) | ((unsigned)f2bf(v1.w) << 16);
        *(uint4*)((char*)xs + row * 256 + ch * 16) = p;
    }
    __syncthreads();
    int g = t >> 6, l = t & 63;
    int coll = l & 15, hi = l >> 4;
    bf16x8 a[4];
#pragma unroll
    for (int k = 0; k < 4; ++k) {   // A-frag: row=l&15, k0 = k*32 + hi*8
        int ch = (k * 4 + hi) ^ (coll & 7);
        a[k] = *(const bf16x8*)((const char*)xs + coll * 256 + ch * 16);
    }
    const bf16x8* wf = (const bf16x8*)W1f;
    f32x4 acc[4];
#pragma unroll
    for (int ct = 0; ct < 4; ++ct) {
        f32x4 c = {0.f, 0.f, 0.f, 0.f};
#pragma unroll
        for (int k = 0; k < 4; ++k) {
            bf16x8 b = wf[((g * 4 + ct) * 4 + k) * 64 + l];
            c = __builtin_amdgcn_mfma_f32_16x16x32_bf16(a[k], b, c, 0, 0, 0);
        }
        acc[ct] = c;
    }
    // a_src/a_dst for head g from fp32 accs (C/D: row=hi*4+r, col=64g+16ct+coll)
    float ps[4] = {0,0,0,0}, pd[4] = {0,0,0,0};
#pragma unroll
    for (int ct = 0; ct < 4; ++ct) {
        float as_ = attsrc[g * 64 + ct * 16 + coll];
        float ad_ = attdst[g * 64 + ct * 16 + coll];
#pragma unroll
        for (int r = 0; r < 4; ++r) {
            ps[r] += acc[ct][r] * as_;
            pd[r] += acc[ct][r] * ad_;
        }
    }
#pragma unroll
    for (int r = 0; r < 4; ++r)
#pragma unroll
        for (int m = 1; m < 16; m <<= 1) {
            ps[r] += __shfl_xor(ps[r], m);
            pd[r] += __shfl_xor(pd[r], m);
        }
    if (coll == 0) {
#pragma unroll
        for (int r = 0; r < 4; ++r) {
            int row = hi * 4 + r;
            a_src[(n0 + row) * H1 + g] = ps[r];
            a_dst[(n0 + row) * H1 + g] = pd[r];
        }
    }
    // repack h1 bf16 via LDS (col swizzle: chunk ^= row&3)
#pragma unroll
    for (int ct = 0; ct < 4; ++ct)
#pragma unroll
        for (int r = 0; r < 4; ++r) {
            int row = hi * 4 + r;
            int col = (g * 64 + ct * 16 + coll) ^ ((row & 3) << 4);
            hs[row * 256 + col] = f2bf(acc[ct][r]);
        }
    __syncthreads();
    {
        int row = t >> 4;
        int chS = (t & 15) ^ (row & 3);
        const uint4* sp = (const uint4*)(hs + row * 256 + chS * 16);
        uint4* dp = (uint4*)(h1b + (size_t)(n0 + row) * HC + (t & 15) * 16);
        dp[0] = sp[0]; dp[1] = sp[1];
    }
}

// ---------- layer 1 aggregation: ONE WAVE PER NODE, bf16 row gather (uint2/lane) ----------
__global__ void k_agg1(const int* __restrict__ rowstart, const int* __restrict__ deg,
                       const int2* __restrict__ csr,
                       const float* __restrict__ a_src, const float* __restrict__ a_dst,
                       const float* __restrict__ scal, const unsigned short* __restrict__ h1b,
                       const float* __restrict__ b1, float* __restrict__ out1) {
    __shared__ float4 wlds[4][64];
    int wid = threadIdx.x >> 6, lane = threadIdx.x & 63;
    int n = blockIdx.x * 4 + wid;
    int myh = lane >> 4;
    int rs = rowstart[n], cnt = deg[n];
    const float4 adv = ((const float4*)a_dst)[n];
    const float4 wh  = *((const float4*)(scal + 4));
    const uint2* h1v = (const uint2*)h1b;
    const float* wbase = (const float*)(&wlds[wid][0]) + myh;

    float4 M = make_float4(-INFINITY, -INFINITY, -INFINITY, -INFINITY);
    float4 den  = make_float4(0.f, 0.f, 0.f, 0.f);
    float4 acc0 = make_float4(0.f, 0.f, 0.f, 0.f);
    float4 acc1 = make_float4(0.f, 0.f, 0.f, 0.f);

    for (int base = 0; base < cnt; base += 64) {
        int j = base + lane;
        int sj = 0;
        float4 al = make_float4(-INFINITY, -INFINITY, -INFINITY, -INFINITY);
        if (j < cnt) {
            int2 cv = csr[rs + j];
            sj = cv.x;
            float ea = __int_as_float(cv.y);
            float4 as4 = ((const float4*)a_src)[sj];
            al.x = as4.x + adv.x + ea * wh.x;
            al.y = as4.y + adv.y + ea * wh.y;
            al.z = as4.z + adv.z + ea * wh.z;
            al.w = as4.w + adv.w + ea * wh.w;
            al.x = al.x > 0.f ? al.x : NEG_SLOPE * al.x;
            al.y = al.y > 0.f ? al.y : NEG_SLOPE * al.y;
            al.z = al.z > 0.f ? al.z : NEG_SLOPE * al.z;
            al.w = al.w > 0.f ? al.w : NEG_SLOPE * al.w;
        }
        float4 cm = bcast4(wredmax4(al));
        float4 newM = make_float4(fmaxf(M.x, cm.x), fmaxf(M.y, cm.y),
                                  fmaxf(M.z, cm.z), fmaxf(M.w, cm.w));
        float4 sc = make_float4(__expf(M.x - newM.x), __expf(M.y - newM.y),
                                __expf(M.z - newM.z), __expf(M.w - newM.w));
        den.x *= sc.x; den.y *= sc.y; den.z *= sc.z; den.w *= sc.w;
        float scm = comp4(sc, myh);
        acc0.x *= scm; acc0.y *= scm; acc0.z *= scm; acc0.w *= scm;
        acc1.x *= scm; acc1.y *= scm; acc1.z *= scm; acc1.w *= scm;
        M = newM;
        float4 w4 = make_float4(__expf(al.x - M.x), __expf(al.y - M.y),
                                __expf(al.z - M.z), __expf(al.w - M.w));
        den.x += w4.x; den.y += w4.y; den.z += w4.z; den.w += w4.w;
        wlds[wid][lane] = w4;
        int m = min(64, cnt - base);
        int jj = 0;
#pragma unroll 2
        for (; jj + 1 < m; jj += 2) {
            int s0 = __shfl(sj, jj);
            int s1 = __shfl(sj, jj + 1);
            float w0 = wbase[jj * 4];
            float w1 = wbase[jj * 4 + 4];
            uint2 v0 = h1v[(size_t)s0 * 64 + lane];
            uint2 v1 = h1v[(size_t)s1 * 64 + lane];
            acc0.x += __uint_as_float(v0.x << 16)          * w0;
            acc0.y += __uint_as_float(v0.x & 0xffff0000u)  * w0;
            acc0.z += __uint_as_float(v0.y << 16)          * w0;
            acc0.w += __uint_as_float(v0.y & 0xffff0000u)  * w0;
            acc1.x += __uint_as_float(v1.x << 16)          * w1;
            acc1.y += __uint_as_float(v1.x & 0xffff0000u)  * w1;
            acc1.z += __uint_as_float(v1.y << 16)          * w1;
            acc1.w += __uint_as_float(v1.y & 0xffff0000u)  * w1;
        }
        if (jj < m) {
            int s0 = __shfl(sj, jj);
            float w0 = wbase[jj * 4];
            uint2 v0 = h1v[(size_t)s0 * 64 + lane];
            acc0.x += __uint_as_float(v0.x << 16)          * w0;
            acc0.y += __uint_as_float(v0.x & 0xffff0000u)  * w0;
            acc0.z += __uint_as_float(v0.y << 16)          * w0;
            acc0.w += __uint_as_float(v0.y & 0xffff0000u)  * w0;
        }
    }
    float4 dsum = bcast4(wredsum4(den));
    float dt = comp4(dsum, myh) + EPSF;
    float inv = 1.0f / dt;
    float4 b4 = ((const float4*)b1)[lane];
    float4 v;
    v.x = (acc0.x + acc1.x) * inv + b4.x;
    v.y = (acc0.y + acc1.y) * inv + b4.y;
    v.z = (acc0.z + acc1.z) * inv + b4.z;
    v.w = (acc0.w + acc1.w) * inv + b4.w;
    v.x = v.x > 0.f ? v.x : expm1f(v.x);
    v.y = v.y > 0.f ? v.y : expm1f(v.y);
    v.z = v.z > 0.f ? v.z : expm1f(v.z);
    v.w = v.w > 0.f ? v.w : expm1f(v.w);
    ((float4*)(out1 + (size_t)n * HC))[lane] = v;
}

// ---------- layer 2 GEMM via MFMA: h2(bf16) = out1 @ W2 ----------
// 16 rows/block, 4 waves; wave g = col-tile g (cols 16g..16g+15); K=256 = 8 k-steps
__global__ void k_gemm2(const float* __restrict__ out1, const unsigned short* __restrict__ W2f,
                        const float* __restrict__ attsrc, const float* __restrict__ attdst,
                        unsigned short* __restrict__ h2b,
                        float* __restrict__ a_src2, float* __restrict__ a_dst2) {
    __shared__ unsigned short xs2[16 * 256];   // 8 KB, swizzled
    __shared__ unsigned short hs2[16 * 64];    // 2 KB
    __shared__ float pls[2][4][16];
    int t = threadIdx.x;
    int n0 = blockIdx.x * 16;
    {   // stage-convert out1 -> bf16 LDS (thread t: row t>>4, chunks 2(t&15), 2(t&15)+1)
        const float4* og = (const float4*)(out1 + (size_t)n0 * HC);
        float4 v0 = og[t * 4], v1 = og[t * 4 + 1], v2 = og[t * 4 + 2], v3 = og[t * 4 + 3];
        int row = t >> 4;
        int c0 = ((t & 15) * 2) ^ (row & 7);
        int c1 = ((t & 15) * 2 + 1) ^ (row & 7);
        uint4 p0, p1;
        p0.x = f2bf(v0.x) | ((unsigned)f2bf(v0.y) << 16);
        p0.y = f2bf(v0.z) | ((unsigned)f2bf(v0.w) << 16);
        p0.z = f2bf(v1.x) | ((unsigned)f2bf(v1.y) << 16);
        p0.w = f2bf(v1.z) | ((unsigned)f2bf(v1.w) << 16);
        p1.x = f2bf(v2.x) | ((unsigned)f2bf(v2.y) << 16);
        p1.y = f2bf(v2.z) | ((unsigned)f2bf(v2.w) << 16);
        p1.z = f2bf(v3.x) | ((unsigned)f2bf(v3.y) << 16);
        p1.w = f2bf(v3.z) | ((unsigned)f2bf(v3.w) << 16);
        *(uint4*)((char*)xs2 + row * 512 + c0 * 16) = p0;
        *(uint4*)((char*)xs2 + row * 512 + c1 * 16) = p1;
    }
    __syncthreads();
    int g = t >> 6, l = t & 63;
    int coll = l & 15, hi = l >> 4;
    const bf16x8* wf = (const bf16x8*)W2f;
    f32x4 acc = {0.f, 0.f, 0.f, 0.f};
#pragma unroll
    for (int k = 0; k < 8; ++k) {
        int ch = (k * 4 + hi) ^ (coll & 7);
        bf16x8 av = *(const bf16x8*)((const char*)xs2 + coll * 512 + ch * 16);
        bf16x8 bv = wf[(g * 8 + k) * 64 + l];
        acc = __builtin_amdgcn_mfma_f32_16x16x32_bf16(av, bv, acc, 0, 0, 0);
    }
    // partial a_src2/a_dst2 (wave covers 16 cols) from fp32 accs
    float as_ = attsrc[g * 16 + coll];
    float ad_ = attdst[g * 16 + coll];
    float ps[4], pd[4];
#pragma unroll
    for (int r = 0; r < 4; ++r) { ps[r] = acc[r] * as_; pd[r] = acc[r] * ad_; }
#pragma unroll
    for (int r = 0; r < 4; ++r)
#pragma unroll
        for (int m = 1; m < 16; m <<= 1) {
            ps[r] += __shfl_xor(ps[r], m);
            pd[r] += __shfl_xor(pd[r], m);
        }
    if (coll == 0) {
#pragma unroll
        for (int r = 0; r < 4; ++r) {
            int row = hi * 4 + r;
            pls[0][g][row] = ps[r];
            pls[1][g][row] = pd[r];
        }
    }
    // h2 repack (col swizzle: 16-short section ^= row&3)
#pragma unroll
    for (int r = 0; r < 4; ++r) {
        int row = hi * 4 + r;
        int col = (g * 16 + coll) ^ ((row & 3) << 4);
        hs2[row * 64 + col] = f2bf(acc[r]);
    }
    __syncthreads();
    if (t < 128) {
        int row = t >> 3;
        int chS = (t & 7) ^ ((row & 3) << 1);
        *(uint4*)(h2b + (size_t)(n0 + row) * C + (t & 7) * 8) =
            *(const uint4*)(hs2 + row * 64 + chS * 8);
    }
    if (t < 16) {
        a_src2[n0 + t] = pls[0][0][t] + pls[0][1][t] + pls[0][2][t] + pls[0][3][t];
        a_dst2[n0 + t] = pls[1][0][t] + pls[1][1][t] + pls[1][2][t] + pls[1][3][t];
    }
}

// ---------- layer 2 aggregation + classifier head: ONE WAVE PER NODE, bf16 gather ----------
__global__ void k_agg2(const int* __restrict__ rowstart, const int* __restrict__ deg,
                       const int2* __restrict__ csr,
                       const float* __restrict__ a_src2, const float* __restrict__ a_dst2,
                       const float* __restrict__ scal, const unsigned short* __restrict__ h2b,
                       const float* __restrict__ b2, const float* __restrict__ Wfc,
                       const float* __restrict__ bfc, float* __restrict__ d_out, int N) {
    __shared__ float wlds[4][64];
    int wid = threadIdx.x >> 6, lane = threadIdx.x & 63;
    int n = blockIdx.x * 4 + wid;
    int eg = lane >> 4, li = lane & 15;
    int rs = rowstart[n], cnt = deg[n];
    float adv = a_dst2[n];
    float w2  = scal[2];
    const uint2* h2v = (const uint2*)h2b;

    float M = -INFINITY, den = 0.0f;
    float4 acc = make_float4(0.f, 0.f, 0.f, 0.f);

    for (int base = 0; base < cnt; base += 64) {
        int j = base + lane;
        int sj = 0; float al = -INFINITY;
        if (j < cnt) {
            int2 cv = csr[rs + j];
            sj = cv.x;
            al = a_src2[sj] + adv + __int_as_float(cv.y) * w2;
            al = al > 0.0f ? al : NEG_SLOPE * al;
        }
        float cm = wredmax(al); cm = __shfl(cm, 0);
        float newM = fmaxf(M, cm);
        float sc = __expf(M - newM);
        den *= sc;
        acc.x *= sc; acc.y *= sc; acc.z *= sc; acc.w *= sc;
        M = newM;
        float w = __expf(al - M);
        den += w;
        wlds[wid][lane] = w;
        int m = min(64, cnt - base);
#pragma unroll 4
        for (int jj = 0; jj < m; jj += 4) {
            int idx = jj + eg;
            float ww = wlds[wid][idx];
            int   s  = __shfl(sj, idx);
            uint2 hv = h2v[(size_t)s * 16 + li];
            acc.x += __uint_as_float(hv.x << 16)         * ww;
            acc.y += __uint_as_float(hv.x & 0xffff0000u) * ww;
            acc.z += __uint_as_float(hv.y << 16)         * ww;
            acc.w += __uint_as_float(hv.y & 0xffff0000u) * ww;
        }
    }
#pragma unroll
    for (int off = 32; off >= 16; off >>= 1) {
        acc.x += __shfl_down(acc.x, off);
        acc.y += __shfl_down(acc.y, off);
        acc.z += __shfl_down(acc.z, off);
        acc.w += __shfl_down(acc.w, off);
    }
    float dt = wredsum(den); dt = __shfl(dt, 0);
    float inv = 1.0f / (dt + EPSF);
    float4 b4 = ((const float4*)b2)[li];
    float4 v;
    v.x = acc.x * inv + b4.x;
    v.y = acc.y * inv + b4.y;
    v.z = acc.z * inv + b4.z;
    v.w = acc.w * inv + b4.w;
    v.x = v.x > 0.f ? v.x : expm1f(v.x);
    v.y = v.y > 0.f ? v.y : expm1f(v.y);
    v.z = v.z > 0.f ? v.z : expm1f(v.z);
    v.w = v.w > 0.f ? v.w : expm1f(v.w);
    if (lane < 16)
        ((float4*)(d_out + (size_t)2 * N + (size_t)n * C))[li] = v;   // emb
    const float4* wfc4 = (const float4*)Wfc;
    float4 A = wfc4[li * 2], B = wfc4[li * 2 + 1];
    float p0 = v.x * A.x + v.y * A.z + v.z * B.x + v.w * B.z;
    float p1 = v.x * A.y + v.y * A.w + v.z * B.y + v.w * B.w;
#pragma unroll
    for (int off = 8; off; off >>= 1) {
        p0 += __shfl_down(p0, off);
        p1 += __shfl_down(p1, off);
    }
    if (lane == 0) {
        p0 += bfc[0]; p1 += bfc[1];
        float mm = fmaxf(p0, p1);
        float lse = mm + logf(__expf(p0 - mm) + __expf(p1 - mm));
        d_out[(size_t)n * 2]     = p0 - lse;
        d_out[(size_t)n * 2 + 1] = p1 - lse;
    }
}

extern "C" void kernel_launch(void* const* d_in, const int* in_sizes, int n_in,
                              void* d_out, int out_size, void* d_ws, size_t ws_size,
                              hipStream_t stream) {
    const float* x     = (const float*)d_in[0];
    const int*   ei    = (const int*)  d_in[1];
    const float* eattr = (const float*)d_in[2];
    const float* W1    = (const float*)d_in[3];
    const float* as1   = (const float*)d_in[4];
    const float* ad1   = (const float*)d_in[5];
    const float* We1   = (const float*)d_in[6];
    const float* ae1   = (const float*)d_in[7];
    const float* b1    = (const float*)d_in[8];
    const float* W2    = (const float*)d_in[9];
    const float* as2   = (const float*)d_in[10];
    const float* ad2   = (const float*)d_in[11];
    const float* We2   = (const float*)d_in[12];
    const float* ae2   = (const float*)d_in[13];
    const float* b2    = (const float*)d_in[14];
    const float* Wfc   = (const float*)d_in[15];
    const float* bfc   = (const float*)d_in[16];

    const int N    = in_sizes[0] / FIN;   // 50000
    const int E    = in_sizes[2];         // 800000
    const int Etot = E + N;

    char* wsb = (char*)d_ws;
    size_t off = 0;
    auto alloc = [&](size_t elems) {
        off = (off + 15) & ~(size_t)15;   // 16B align
        void* p = wsb + off; off += elems * 4; return p;
    };

    // ---- zero-initialized region (front) ----
    int*   deg    = (int*)  alloc(N);
    int*   cursor = (int*)  alloc(N);
    float* scal   = (float*)alloc(8);
    size_t zero_bytes = (off + 15) & ~(size_t)15;
    // ---- rest ----
    int*   rowstart = (int*)  alloc(N);
    int*   bsums    = (int*)  alloc(256);
    int2*  csr      = (int2*) alloc((size_t)Etot * 2);
    unsigned short* h1b = (unsigned short*)alloc((size_t)N * HC / 2);   // bf16
    unsigned short* h2b = (unsigned short*)alloc((size_t)N * C / 2);    // bf16
    float* out1     = (float*)alloc((size_t)N * HC);
    unsigned short* W1f = (unsigned short*)alloc(16384);   // 32768 bf16
    unsigned short* W2f = (unsigned short*)alloc(8192);    // 16384 bf16
    float* a_src1   = (float*)alloc((size_t)N * H1);
    float* a_dst1   = (float*)alloc((size_t)N * H1);
    float* a_src2   = (float*)alloc(N);
    float* a_dst2   = (float*)alloc(N);

    hipMemsetAsync(d_ws, 0, zero_bytes, stream);

    k_ea_sum<<<(E + 255) / 256, 256, 0, stream>>>(eattr, E, scal);
    k_prep<<<1, 256, 0, stream>>>(We1, ae1, We2, ae2, scal, 1.0f / (float)E);
    k_convw<<<128, 256, 0, stream>>>(W1, W2, W1f, W2f);

    int ge = (Etot + 255) / 256;
    int nb = (N + 255) / 256;
    k_hist<<<ge, 256, 0, stream>>>(ei, deg, E, Etot);
    k_scan1<<<nb, 256, 0, stream>>>(deg, rowstart, bsums, N);
    k_scan2<<<1, 256, 0, stream>>>(bsums, nb);
    k_scan3<<<nb, 256, 0, stream>>>(rowstart, bsums, N);
    k_scatter<<<ge, 256, 0, stream>>>(ei, eattr, scal, rowstart, cursor, csr, E, Etot);

    k_gemm1<<<N / 16, 256, 0, stream>>>(x, W1f, as1, ad1, h1b, a_src1, a_dst1);
    k_agg1<<<N / 4, 256, 0, stream>>>(rowstart, deg, csr, a_src1, a_dst1, scal, h1b, b1, out1);
    k_gemm2<<<N / 16, 256, 0, stream>>>(out1, W2f, as2, ad2, h2b, a_src2, a_dst2);
    k_agg2<<<N / 4, 256, 0, stream>>>(rowstart, deg, csr, a_src2, a_dst2, scal, h2b,
                                      b2, Wfc, bfc, (float*)d_out, N);
}